// Round 5
// baseline (2682.177 us; speedup 1.0000x reference)
//
#include <hip/hip_runtime.h>

typedef _Float16 h2 __attribute__((ext_vector_type(2)));
typedef float f4 __attribute__((ext_vector_type(4)));

static constexpr int NB = 128;   // batch
static constexpr int NT = 4096;  // time
static constexpr int NI = 64;    // input
static constexpr int NH = 256;   // hidden
static constexpr int NO = 64;    // output
static constexpr int CHUNK = 16; // timesteps of xp staged per LDS chunk
static constexpr size_t XP_BYTES = (size_t)NB * NT * NH * 2;  // fp16 xp in d_ws

union H2I { int i; h2 h; };

__device__ __forceinline__ float fdot2(h2 a, h2 b, float c) {
#if __has_builtin(__builtin_amdgcn_fdot2)
    return __builtin_amdgcn_fdot2(a, b, c, false);
#else
    return c + (float)a[0] * (float)b[0] + (float)a[1] * (float)b[1];
#endif
}

__device__ __forceinline__ int pack2(float a, float b) {
    H2I u;
    u.h[0] = (_Float16)a;
    u.h[1] = (_Float16)b;
    return u.i;
}
__device__ __forceinline__ h2 toh2(int v) { H2I u; u.i = v; return u.h; }

// lane^8 combine on the VALU pipe (DPP row_ror:8 within 16-lane rows)
__device__ __forceinline__ float red_xor8(float v) {
#if __has_builtin(__builtin_amdgcn_mov_dpp)
    int o = __builtin_amdgcn_mov_dpp(__float_as_int(v), 0x128, 0xF, 0xF, true);
    return v + __int_as_float(o);
#else
    return v + __shfl_xor(v, 8, 64);
#endif
}
// gfx950 VALU cross-lane swaps (both operands modified):
// after swap32: a=[a_lo,b_lo], b=[a_hi,b_hi]  (32-lane halves)
__device__ __forceinline__ void swap32(float& a, float& b) {
    asm("v_permlane32_swap_b32 %0, %1" : "+v"(a), "+v"(b));
}
// after swap16: a=[a0,b0,a2,b2], b=[a1,b1,a3,b3]  (16-lane groups)
__device__ __forceinline__ void swap16(float& a, float& b) {
    asm("v_permlane16_swap_b32 %0, %1" : "+v"(a), "+v"(b));
}
// xor-16 via ds_swizzle (fallback path only)
__device__ __forceinline__ float red_xor16_ds(float v) {
#if __has_builtin(__builtin_amdgcn_ds_swizzle)
    int o = __builtin_amdgcn_ds_swizzle(__float_as_int(v), 0x401F);
    return v + __int_as_float(o);
#else
    return v + __shfl_xor(v, 16, 64);
#endif
}

__device__ __forceinline__ float fast_tanh(float x) {
#if __has_builtin(__builtin_amdgcn_exp2f)
    float e = __builtin_amdgcn_exp2f(x * 2.885390081777927f); // 2*log2(e)
#else
    float e = exp2f(x * 2.885390081777927f);
#endif
#if __has_builtin(__builtin_amdgcn_rcpf)
    return 1.0f - 2.0f * __builtin_amdgcn_rcpf(e + 1.0f);
#else
    return 1.0f - 2.0f / (e + 1.0f);
#endif
}

// ======================= pass 1: xp = x @ Wih^T + b_ih + b_hh (fp16) =======================
// 256 blocks x 256 threads. Block (b, half): 2048 timesteps. Lane owns rows j=4l..4l+3 of Wih.
__global__ __launch_bounds__(256, 1) void xp_pre(
    const float* __restrict__ x, const float* __restrict__ wih,
    const float* __restrict__ bih, const float* __restrict__ bhh,
    int* __restrict__ xpg)
{
    __shared__ int xs[64 * 32];   // 8 KB: chunk of x, fp16 [64 t][64 i]
    __shared__ int os[64 * 128];  // 32 KB: chunk of xp, fp16 [64 t][256 j]

    const int tid = threadIdx.x;
    const int w = tid >> 6, l = tid & 63;
    const int b = blockIdx.x >> 1;
    const int t0 = (blockIdx.x & 1) * (NT / 2);

    h2 wr[4][32];  // Wih rows 4l..4l+3 as fp16 pairs (128 VGPRs)
    float bs[4];
#pragma unroll
    for (int a = 0; a < 4; ++a) {
        const int j = 4 * l + a;
        const f4* src = (const f4*)(wih + (size_t)j * NI);
#pragma unroll
        for (int u = 0; u < 16; ++u) {
            f4 v = src[u];
            wr[a][2 * u]     = toh2(pack2(v.x, v.y));
            wr[a][2 * u + 1] = toh2(pack2(v.z, v.w));
        }
        bs[a] = bih[j] + bhh[j];
    }

    const float* xbase = x + ((size_t)b * NT + t0) * NI;
    const int NCH = (NT / 2) / 64;  // 32 chunks of 64 timesteps

    f4 ld[4];  // staged 16 floats / thread
#pragma unroll
    for (int k = 0; k < 4; ++k) ld[k] = ((const f4*)xbase)[tid * 4 + k];

    for (int ch = 0; ch < NCH; ++ch) {
        // commit staged chunk to LDS as fp16
        {
            int4 w0, w1;
            w0.x = pack2(ld[0].x, ld[0].y); w0.y = pack2(ld[0].z, ld[0].w);
            w0.z = pack2(ld[1].x, ld[1].y); w0.w = pack2(ld[1].z, ld[1].w);
            w1.x = pack2(ld[2].x, ld[2].y); w1.y = pack2(ld[2].z, ld[2].w);
            w1.z = pack2(ld[3].x, ld[3].y); w1.w = pack2(ld[3].z, ld[3].w);
            *(int4*)&xs[tid * 8] = w0;
            *(int4*)&xs[tid * 8 + 4] = w1;
        }
        __syncthreads();
        // prefetch next chunk
        if (ch + 1 < NCH) {
            const f4* nx = (const f4*)(xbase + (size_t)(ch + 1) * 64 * NI);
#pragma unroll
            for (int k = 0; k < 4; ++k) ld[k] = nx[tid * 4 + k];
        }
        // compute: wave w handles t_local = tt*4 + w
#pragma unroll 1
        for (int tt = 0; tt < 16; ++tt) {
            const int tl = tt * 4 + w;
            const int4* xr = (const int4*)&xs[tl * 32];
            int4 xv[8];
#pragma unroll
            for (int u = 0; u < 8; ++u) xv[u] = xr[u];
            const int* xd = (const int*)xv;
            float acc[4] = {0.f, 0.f, 0.f, 0.f};
#pragma unroll
            for (int kk = 0; kk < 32; ++kk) {
                const h2 hv = toh2(xd[kk]);
#pragma unroll
                for (int a = 0; a < 4; ++a) acc[a] = fdot2(wr[a][kk], hv, acc[a]);
            }
            int2 pk;
            pk.x = pack2(acc[0] + bs[0], acc[1] + bs[1]);
            pk.y = pack2(acc[2] + bs[2], acc[3] + bs[3]);
            *(int2*)&os[tl * 128 + l * 2] = pk;
        }
        __syncthreads();
        // bulk write chunk of xp (coalesced)
        {
            int4* dst = (int4*)xpg + (size_t)(b * NT + t0 + ch * 64) * 32;
            const int4* s4 = (const int4*)os;
#pragma unroll
            for (int k = 0; k < 8; ++k) dst[k * 256 + tid] = s4[k * 256 + tid];
        }
        __syncthreads();
    }
}

// ======================= pass 2: recurrence =======================
__global__ __launch_bounds__(256, 1) void rnn_rec(
    const int* __restrict__ xpg,   // fp16 xp [B][T][H]
    const float* __restrict__ whhg,
    const float* __restrict__ wy, const float* __restrict__ by,
    float* __restrict__ out)
{
    __shared__ int hbuf[2][NH / 2];           // h fp16, chunk-swizzled: 2 x 512 B
    __shared__ int xps[2][CHUNK * NH / 2];    // xp chunks: 2 x 8 KB
    __shared__ float hf[NH];

    const int tid = threadIdx.x;
    const int w = tid >> 6;      // wave: outputs [64w, 64w+64)
    const int l = tid & 63;
    const int r = l & 7;
    const int q = l >> 3;        // K-eighth: h[32q..32q+31]
    const int b5 = l >> 5;
    const int b = blockIdx.x;

    // W_hh rows j0..j0+7, my K-slice (128 VGPRs as fp16 pairs)
    h2 whh[8][16];
    const int j0 = 64 * w + 8 * r;
#pragma unroll
    for (int a = 0; a < 8; ++a) {
        const f4* src = (const f4*)(whhg + (size_t)(j0 + a) * NH + 32 * q);
#pragma unroll
        for (int u = 0; u < 8; ++u) {
            f4 v = src[u];
            whh[a][2 * u]     = toh2(pack2(v.x, v.y));
            whh[a][2 * u + 1] = toh2(pack2(v.z, v.w));
        }
    }
    const int jb = j0 + 4 * b5;  // my 4 finished outputs after reduce

    // swizzled h addresses (identical scheme to R4 kernel)
    const int sw = q & 3;
    int hoff[4];
#pragma unroll
    for (int c = 0; c < 4; ++c) hoff[c] = 64 * q + 16 * (c ^ sw);
    const int qh = 2 * w + (r >> 2);
    const int pub_off = 64 * qh + 16 * ((r & 3) ^ (qh & 3)) + 8 * b5;
    const bool writer = (l & 24) == 0;

    // stage xp chunk 0
    {
        const int4* g4 = (const int4*)xpg;
        const size_t base4 = (size_t)b * NT * 32;
        *(int4*)&xps[0][tid * 4]        = g4[base4 + tid];
        *(int4*)&xps[0][tid * 4 + 1024] = g4[base4 + tid + 256];
    }
    if (tid < NH / 2) hbuf[0][tid] = 0;  // h(0)=0
    __syncthreads();

    int4 xq0, xq1;
    int p = 0;

#pragma unroll 1
    for (int t = 0; t < NT; ++t) {
        const int s = t & (CHUNK - 1);
        const int c = t >> 4;

        if (s == 0 && t + CHUNK < NT) {
            const int4* g4 = (const int4*)xpg;
            const size_t base4 = ((size_t)b * NT + t + CHUNK) * 32;
            xq0 = g4[base4 + tid];
            xq1 = g4[base4 + tid + 256];
        }

        const char* hbp = (const char*)hbuf[p];
        const int4 h0 = *(const int4*)(hbp + hoff[0]);
        const int4 h1 = *(const int4*)(hbp + hoff[1]);
        const int4 h2v = *(const int4*)(hbp + hoff[2]);
        const int4 h3 = *(const int4*)(hbp + hoff[3]);
        const int2 hx = *(const int2*)&xps[c & 1][s * 128 + (jb >> 1)];

        float acc[8];
#pragma unroll
        for (int a = 0; a < 8; ++a) acc[a] = 0.f;

        const int hc[16] = {h0.x, h0.y, h0.z, h0.w, h1.x, h1.y, h1.z, h1.w,
                            h2v.x, h2v.y, h2v.z, h2v.w, h3.x, h3.y, h3.z, h3.w};
#pragma unroll
        for (int kk = 0; kk < 16; ++kk) {
            const h2 hv = toh2(hc[kk]);
#pragma unroll
            for (int a = 0; a < 8; ++a) acc[a] = fdot2(whh[a][kk], hv, acc[a]);
        }

        // all-VALU reduction over lane bits 5,3,4 + xp add + tanh
        const h2 xlo = toh2(hx.x), xhi = toh2(hx.y);
        const float xpf[4] = {(float)xlo[0], (float)xlo[1], (float)xhi[0], (float)xhi[1]};
        float th[4];
#pragma unroll
        for (int i = 0; i < 4; ++i) {
            float a0 = acc[i], a1 = acc[i + 4];
            swap32(a0, a1);          // bit5 pair-combine
            float s5 = a0 + a1;      // lanes<32: acc[i] xor32-reduced; >=32: acc[i+4]
            s5 = red_xor8(s5);       // bit3 (DPP)
            float u0 = s5, u1 = s5;
            swap16(u0, u1);          // bit4 butterfly
            th[i] = fast_tanh((u0 + u1) + xpf[i]);
        }

        if (writer) {
            int2 pk;
            pk.x = pack2(th[0], th[1]);
            pk.y = pack2(th[2], th[3]);
            *(int2*)((char*)hbuf[p ^ 1] + pub_off) = pk;
            if (t == NT - 1) {
                f4 hv;
                hv.x = th[0]; hv.y = th[1]; hv.z = th[2]; hv.w = th[3];
                *(f4*)(&hf[jb]) = hv;
            }
        }

        if (s == CHUNK - 1 && t + 1 < NT) {
            *(int4*)&xps[(c + 1) & 1][tid * 4]        = xq0;
            *(int4*)&xps[(c + 1) & 1][tid * 4 + 1024] = xq1;
        }

        __syncthreads();
        p ^= 1;
    }

    // epilogue: y = h_last @ W_y^T + b_y
    if (tid < NO) {
        float accy = by[tid];
        const f4* wrow = (const f4*)(wy + (size_t)tid * NH);
        const f4* hp = (const f4*)hf;
#pragma unroll
        for (int u = 0; u < NH / 4; ++u) {
            f4 wv = wrow[u];
            f4 hv = hp[u];
            accy += wv.x * hv.x + wv.y * hv.y + wv.z * hv.z + wv.w * hv.w;
        }
        out[b * NO + tid] = accy;
    }
}

// ======================= fallback (R4 kernel, used if d_ws too small) =======================
__global__ __launch_bounds__(256, 1) void rnn_persist_fb(
    const float* __restrict__ x, const float* __restrict__ wih,
    const float* __restrict__ whhg, const float* __restrict__ bih,
    const float* __restrict__ bhh, const float* __restrict__ wy,
    const float* __restrict__ by, float* __restrict__ out)
{
    __shared__ int hbuf[2][NH / 2];
    __shared__ int xbuf[2][CHUNK * NI / 2];
    __shared__ float hf[NH];

    const int tid = threadIdx.x;
    const int w = tid >> 6;
    const int l = tid & 63;
    const int r = l & 7;
    const int q = l >> 3;
    const int b5 = l >> 5;
    const bool hi32 = (l >= 32);
    const int b = blockIdx.x;

    h2 whh[8][16];
    h2 wi[8][4];
    const int j0 = 64 * w + 8 * r;
#pragma unroll
    for (int a = 0; a < 8; ++a) {
        const f4* src = (const f4*)(whhg + (size_t)(j0 + a) * NH + 32 * q);
#pragma unroll
        for (int u = 0; u < 8; ++u) {
            f4 v = src[u];
            whh[a][2 * u]     = toh2(pack2(v.x, v.y));
            whh[a][2 * u + 1] = toh2(pack2(v.z, v.w));
        }
        const f4* s2 = (const f4*)(wih + (size_t)(j0 + a) * NI + 8 * q);
#pragma unroll
        for (int u = 0; u < 2; ++u) {
            f4 v = s2[u];
            wi[a][2 * u]     = toh2(pack2(v.x, v.y));
            wi[a][2 * u + 1] = toh2(pack2(v.z, v.w));
        }
    }
    const int jb = j0 + 4 * b5;
    float bias_r[4];
#pragma unroll
    for (int i = 0; i < 4; ++i) bias_r[i] = bih[jb + i] + bhh[jb + i];

    const int sw = q & 3;
    int hoff[4];
#pragma unroll
    for (int c = 0; c < 4; ++c) hoff[c] = 64 * q + 16 * (c ^ sw);
    const int qh = 2 * w + (r >> 2);
    const int pub_off = 64 * qh + 16 * ((r & 3) ^ (qh & 3)) + 8 * b5;
    const bool writer = (l & 24) == 0;

    const float* xb = x + (size_t)b * NT * NI;
    {
        f4 v = ((const f4*)xb)[tid];
        xbuf[0][2 * tid]     = pack2(v.x, v.y);
        xbuf[0][2 * tid + 1] = pack2(v.z, v.w);
    }
    if (tid < NH / 2) hbuf[0][tid] = 0;
    __syncthreads();

    f4 xnext;
    int p = 0;

#pragma unroll 1
    for (int t = 0; t < NT; ++t) {
        const int s = t & (CHUNK - 1);
        const int c = t >> 4;
        if (s == 0 && t + CHUNK < NT) {
            xnext = ((const f4*)(xb + (size_t)(t + CHUNK) * NI))[tid];
        }
        const char* hbp = (const char*)hbuf[p];
        const int4 xv = *(const int4*)((const char*)xbuf[c & 1] + 128 * s + 16 * q);
        const int4 h0 = *(const int4*)(hbp + hoff[0]);
        const int4 h1 = *(const int4*)(hbp + hoff[1]);
        const int4 h2v = *(const int4*)(hbp + hoff[2]);
        const int4 h3 = *(const int4*)(hbp + hoff[3]);

        float acc[8];
#pragma unroll
        for (int a = 0; a < 8; ++a) acc[a] = 0.f;
#pragma unroll
        for (int a = 0; a < 8; ++a) {
            acc[a] = fdot2(wi[a][0], toh2(xv.x), acc[a]);
            acc[a] = fdot2(wi[a][1], toh2(xv.y), acc[a]);
            acc[a] = fdot2(wi[a][2], toh2(xv.z), acc[a]);
            acc[a] = fdot2(wi[a][3], toh2(xv.w), acc[a]);
        }
        const int hc[16] = {h0.x, h0.y, h0.z, h0.w, h1.x, h1.y, h1.z, h1.w,
                            h2v.x, h2v.y, h2v.z, h2v.w, h3.x, h3.y, h3.z, h3.w};
#pragma unroll
        for (int kk = 0; kk < 16; ++kk) {
            const h2 hv = toh2(hc[kk]);
#pragma unroll
            for (int a = 0; a < 8; ++a) acc[a] = fdot2(whh[a][kk], hv, acc[a]);
        }
        float th[4];
#pragma unroll
        for (int i = 0; i < 4; ++i) {
            float cc = hi32 ? acc[i + 4] : acc[i];
            float dd = hi32 ? acc[i] : acc[i + 4];
            cc += __shfl_xor(dd, 32, 64);
            cc = red_xor8(cc);
            cc = red_xor16_ds(cc);
            th[i] = fast_tanh(cc + bias_r[i]);
        }
        if (writer) {
            int2 pk;
            pk.x = pack2(th[0], th[1]);
            pk.y = pack2(th[2], th[3]);
            *(int2*)((char*)hbuf[p ^ 1] + pub_off) = pk;
            if (t == NT - 1) {
                f4 hv;
                hv.x = th[0]; hv.y = th[1]; hv.z = th[2]; hv.w = th[3];
                *(f4*)(&hf[jb]) = hv;
            }
        }
        if (s == CHUNK - 1 && t + 1 < NT) {
            xbuf[(c + 1) & 1][2 * tid]     = pack2(xnext.x, xnext.y);
            xbuf[(c + 1) & 1][2 * tid + 1] = pack2(xnext.z, xnext.w);
        }
        __syncthreads();
        p ^= 1;
    }

    if (tid < NO) {
        float accy = by[tid];
        const f4* wrow = (const f4*)(wy + (size_t)tid * NH);
        const f4* hp = (const f4*)hf;
#pragma unroll
        for (int u = 0; u < NH / 4; ++u) {
            f4 wv = wrow[u];
            f4 hv = hp[u];
            accy += wv.x * hv.x + wv.y * hv.y + wv.z * hv.z + wv.w * hv.w;
        }
        out[b * NO + tid] = accy;
    }
}

extern "C" void kernel_launch(void* const* d_in, const int* in_sizes, int n_in,
                              void* d_out, int out_size, void* d_ws, size_t ws_size,
                              hipStream_t stream) {
    const float* x   = (const float*)d_in[0];
    const float* wih = (const float*)d_in[1];
    const float* whh = (const float*)d_in[2];
    const float* bih = (const float*)d_in[3];
    const float* bhh = (const float*)d_in[4];
    const float* wy  = (const float*)d_in[5];
    const float* by  = (const float*)d_in[6];
    float* out = (float*)d_out;

    if (ws_size >= XP_BYTES) {
        xp_pre<<<dim3(256), dim3(256), 0, stream>>>(x, wih, bih, bhh, (int*)d_ws);
        rnn_rec<<<dim3(NB), dim3(256), 0, stream>>>((const int*)d_ws, whh, wy, by, out);
    } else {
        rnn_persist_fb<<<dim3(NB), dim3(256), 0, stream>>>(x, wih, whh, bih, bhh, wy, by, out);
    }
}